// Round 6
// baseline (256.765 us; speedup 1.0000x reference)
//
#include <hip/hip_runtime.h>
#include <hip/hip_bf16.h>

// Problem constants
constexpr int   DIMC  = 512;
constexpr int   PARTC = 6;
constexpr int   NTOK  = 162;
constexpr int   LTOK  = 148;   // tokens cached in LDS as bf16 (148KB); tail from L2
constexpr float SCALING = 22.62741699796952f; // sqrt(512)
constexpr float LNEPS   = 1e-5f;

typedef __attribute__((ext_vector_type(8))) short bf16x8;
typedef __attribute__((ext_vector_type(4))) float f32x4;

// ---------------------------------------------------------------------------
// K0: transpose f32 [R][C] -> bf16 [C][R]
// ---------------------------------------------------------------------------
__global__ __launch_bounds__(256) void transpose_f32_bf16(
    const float* __restrict__ in, __hip_bfloat16* __restrict__ outp, int R, int C)
{
  __shared__ float tile[32][33];
  const int tx = threadIdx.x, ty = threadIdx.y;
  const int bx = blockIdx.x, by = blockIdx.y;
  const int c = bx * 32 + tx;
#pragma unroll
  for (int i = 0; i < 32; i += 8) {
    int r = by * 32 + ty + i;
    tile[ty + i][tx] = in[(size_t)r * C + c];
  }
  __syncthreads();
#pragma unroll
  for (int i = 0; i < 32; i += 8) {
    outp[(size_t)(bx * 32 + ty + i) * R + by * 32 + tx] =
        __float2bfloat16(tile[tx][ty + i]);
  }
}

// ---------------------------------------------------------------------------
// K1 v4: fused attention + /sqrt(512) + LayerNorm.  Block = one b, 512 thr.
// x read from HBM ONCE: Phase A computes f32 logits while stashing bf16 x
// into LDS (148 of 162 tokens; tail re-read from L2 in PV).
//   A : wave-per-token (8 waves): float4 loads, 6 dots, shfl reduce,
//       + pack row to bf16 -> LDS
//   SM: 6 groups x 32 lanes: max / exp / sum (weights unnormalized)
//   PV: thread owns dim t: 148 tokens from LDS (ds_read_u16) + 14 from L2
//   LN: 8-wave reduce, gamma/beta, bf16 out
// LDS ~156KB -> 1 block/CU; grid 1024 = 4 clean rounds.
// ---------------------------------------------------------------------------
__global__ __launch_bounds__(512) void attn_ln_k(
    const float* __restrict__ x,     // [1024][162][512]
    const float* __restrict__ pt,    // [6][512]
    const float* __restrict__ g,     // [512]
    const float* __restrict__ bta,   // [512]
    __hip_bfloat16* __restrict__ outp)
{
  const int b = blockIdx.x;
  const int tid = threadIdx.x;       // 0..511
  const int w = tid >> 6;            // 0..7
  const int lane = tid & 63;
  const float* __restrict__ xb = x + (size_t)b * (NTOK * DIMC);

  __shared__ __align__(16) unsigned short xs[LTOK][DIMC];  // 148 KB bf16
  __shared__ float s_logit[PARTC][NTOK];
  __shared__ __align__(16) float s_w[PARTC][164];          // 164: keeps f32x4 rows aligned
  __shared__ float s_l[PARTC];
  __shared__ float s_red[8][2 * PARTC];

  // pt fragments: lane covers dims [8l, 8l+8)
  float4 pA[PARTC], pB[PARTC];
#pragma unroll
  for (int p = 0; p < PARTC; ++p) {
    pA[p] = *(const float4*)(pt + p * DIMC + 8 * lane);
    pB[p] = *(const float4*)(pt + p * DIMC + 8 * lane + 4);
  }

  // ---- Phase A: logits + bf16 stash.  Wave handles tokens n = w, w+8, ... ----
#pragma unroll 2
  for (int n = w; n < NTOK; n += 8) {
    const float* xr = xb + n * DIMC;
    float4 xa = *(const float4*)(xr + 8 * lane);
    float4 xc = *(const float4*)(xr + 8 * lane + 4);

    if (n < LTOK) {  // wave-uniform branch
      union { unsigned short u[8]; int4 v; } pk;
#pragma unroll
      for (int j = 0; j < 4; ++j) {
        __hip_bfloat16 h0 = __float2bfloat16(((const float*)&xa)[j]);
        __hip_bfloat16 h1 = __float2bfloat16(((const float*)&xc)[j]);
        pk.u[j]     = *(const unsigned short*)&h0;
        pk.u[4 + j] = *(const unsigned short*)&h1;
      }
      *(int4*)(&xs[n][8 * lane]) = pk.v;
    }

    float acc[PARTC];
#pragma unroll
    for (int p = 0; p < PARTC; ++p) {
      acc[p] = xa.x * pA[p].x + xa.y * pA[p].y + xa.z * pA[p].z + xa.w * pA[p].w
             + xc.x * pB[p].x + xc.y * pB[p].y + xc.z * pB[p].z + xc.w * pB[p].w;
    }
#pragma unroll
    for (int off = 32; off > 0; off >>= 1) {
#pragma unroll
      for (int p = 0; p < PARTC; ++p) acc[p] += __shfl_xor(acc[p], off);
    }
    if (lane == 0) {
#pragma unroll
      for (int p = 0; p < PARTC; ++p) s_logit[p][n] = acc[p];
    }
  }
  __syncthreads();

  // ---- Softmax: group (32 threads) per part; shfl widths <=16 stay in-group.
  if (tid < PARTC * 32) {
    const int grp = tid >> 5, gl = tid & 31;
    float m = -1e30f;
    for (int i = gl; i < NTOK; i += 32) m = fmaxf(m, s_logit[grp][i]);
#pragma unroll
    for (int off = 16; off > 0; off >>= 1) m = fmaxf(m, __shfl_xor(m, off));
    float s = 0.f;
    for (int i = gl; i < NTOK; i += 32) {
      float wv = __expf(s_logit[grp][i] - m);
      s_w[grp][i] = wv;
      s += wv;
    }
#pragma unroll
    for (int off = 16; off > 0; off >>= 1) s += __shfl_xor(s, off);
    if (gl == 0) s_l[grp] = s;
  }
  __syncthreads();

  // ---- PV: thread owns dim t.  LDS tokens then L2 tail. ----
  float u[PARTC];
#pragma unroll
  for (int p = 0; p < PARTC; ++p) u[p] = 0.f;

  for (int n0 = 0; n0 < LTOK; n0 += 4) {
    f32x4 wv[PARTC];
#pragma unroll
    for (int p = 0; p < PARTC; ++p) wv[p] = *(const f32x4*)&s_w[p][n0];
#pragma unroll
    for (int j = 0; j < 4; ++j) {
      unsigned short hv = xs[n0 + j][tid];
      float xv = __bfloat162float(*(const __hip_bfloat16*)&hv);
#pragma unroll
      for (int p = 0; p < PARTC; ++p) u[p] += wv[p][j] * xv;
    }
  }
#pragma unroll
  for (int n = LTOK; n < NTOK; ++n) {     // 14 tail rows, L2-warm
    float xv = xb[n * DIMC + tid];
#pragma unroll
    for (int p = 0; p < PARTC; ++p) u[p] += s_w[p][n] * xv;
  }

  // ---- LN: y = u/(l*sqrt(512)); normalize over d (8-wave reduce). ----
  float y0[PARTC], s1[PARTC], s2[PARTC];
#pragma unroll
  for (int p = 0; p < PARTC; ++p) {
    float inv = 1.f / (s_l[p] * SCALING);
    y0[p] = u[p] * inv;
    s1[p] = y0[p];
    s2[p] = y0[p] * y0[p];
  }
#pragma unroll
  for (int off = 32; off > 0; off >>= 1) {
#pragma unroll
    for (int p = 0; p < PARTC; ++p) {
      s1[p] += __shfl_xor(s1[p], off);
      s2[p] += __shfl_xor(s2[p], off);
    }
  }
  if (lane == 0) {
#pragma unroll
    for (int p = 0; p < PARTC; ++p) {
      s_red[w][p] = s1[p];
      s_red[w][PARTC + p] = s2[p];
    }
  }
  __syncthreads();

  const float ga = g[tid], ba = bta[tid];
  __hip_bfloat16* orow = outp + (size_t)b * PARTC * DIMC;
#pragma unroll
  for (int p = 0; p < PARTC; ++p) {
    float S = 0.f, Q = 0.f;
#pragma unroll
    for (int ww = 0; ww < 8; ++ww) {
      S += s_red[ww][p];
      Q += s_red[ww][PARTC + p];
    }
    float mu = S * (1.f / 512.f);
    float var = Q * (1.f / 512.f) - mu * mu;
    float r = rsqrtf(var + LNEPS);
    orow[p * DIMC + tid] = __float2bfloat16((y0[p] - mu) * r * ga + ba);
  }
}

// ---------------------------------------------------------------------------
// MFMA GEMM: C[M][N] = act(A[M][K] @ Bt[N][K]^T + bias)   (unchanged)
// ---------------------------------------------------------------------------
template <int BM, int BN, bool GELU>
__global__ __launch_bounds__(256) void gemm_bt(
    const __hip_bfloat16* __restrict__ A,
    const __hip_bfloat16* __restrict__ Bt,
    const float* __restrict__ bias,
    void* __restrict__ Cv,
    int M, int N, int K)
{
  constexpr int BK = 64;
  constexpr int LDT = BK + 16; // 80 bf16 = 160B row stride
  __shared__ __align__(16) unsigned short Al[BM][LDT];
  __shared__ __align__(16) unsigned short Bl[BN][LDT];

  const int tid = threadIdx.x;
  const int w = tid >> 6, lane = tid & 63;
  const int wr = w >> 1, wc = w & 1;
  const int tm = blockIdx.y * BM, tn = blockIdx.x * BN;
  constexpr int FM = BM / 32, FN = BN / 32;

  f32x4 acc[FM][FN];
#pragma unroll
  for (int m = 0; m < FM; ++m)
#pragma unroll
    for (int n = 0; n < FN; ++n) acc[m][n] = (f32x4){0.f, 0.f, 0.f, 0.f};

  const int srow = tid >> 3;        // 0..31
  const int scol = (tid & 7) * 8;   // element offset in K

  for (int k0 = 0; k0 < K; k0 += BK) {
    __syncthreads();
#pragma unroll
    for (int r = 0; r < BM / 32; ++r) {
      int row = r * 32 + srow;
      *(int4*)(&Al[row][scol]) =
          *(const int4*)(A + (size_t)(tm + row) * K + k0 + scol);
    }
#pragma unroll
    for (int r = 0; r < BN / 32; ++r) {
      int row = r * 32 + srow;
      *(int4*)(&Bl[row][scol]) =
          *(const int4*)(Bt + (size_t)(tn + row) * K + k0 + scol);
    }
    __syncthreads();

#pragma unroll
    for (int kk = 0; kk < 2; ++kk) {
      const int ko = kk * 32 + (lane >> 4) * 8;
      bf16x8 af[FM], bfr[FN];
#pragma unroll
      for (int m = 0; m < FM; ++m)
        af[m] = *(const bf16x8*)(&Al[wr * (BM / 2) + m * 16 + (lane & 15)][ko]);
#pragma unroll
      for (int n = 0; n < FN; ++n)
        bfr[n] = *(const bf16x8*)(&Bl[wc * (BN / 2) + n * 16 + (lane & 15)][ko]);
#pragma unroll
      for (int m = 0; m < FM; ++m)
#pragma unroll
        for (int n = 0; n < FN; ++n)
          acc[m][n] = __builtin_amdgcn_mfma_f32_16x16x32_bf16(
              af[m], bfr[n], acc[m][n], 0, 0, 0);
    }
  }

  // Epilogue: C/D layout col = lane&15, row = (lane>>4)*4 + r  [m89-verified]
  const int cl = lane & 15, rg = (lane >> 4) * 4;
#pragma unroll
  for (int m = 0; m < FM; ++m) {
#pragma unroll
    for (int n = 0; n < FN; ++n) {
      int col = tn + wc * (BN / 2) + n * 16 + cl;
      float bv = bias[col];
#pragma unroll
      for (int r = 0; r < 4; ++r) {
        int row = tm + wr * (BM / 2) + m * 16 + rg + r;
        float v = acc[m][n][r] + bv;
        if (GELU) {
          v = 0.5f * v * (1.f + erff(v * 0.7071067811865476f));
          ((__hip_bfloat16*)Cv)[(size_t)row * N + col] = __float2bfloat16(v);
        } else {
          ((float*)Cv)[(size_t)row * N + col] = v;
        }
      }
    }
  }
}

// ---------------------------------------------------------------------------
extern "C" void kernel_launch(void* const* d_in, const int* in_sizes, int n_in,
                              void* d_out, int out_size, void* d_ws, size_t ws_size,
                              hipStream_t stream)
{
  const float* x   = (const float*)d_in[0];
  const float* pt  = (const float*)d_in[1];
  const float* g   = (const float*)d_in[2];
  const float* bta = (const float*)d_in[3];
  const float* W1  = (const float*)d_in[4];
  const float* b1  = (const float*)d_in[5];
  const float* W2  = (const float*)d_in[6];
  const float* b2  = (const float*)d_in[7];
  float* outp = (float*)d_out;

  char* ws = (char*)d_ws;
  __hip_bfloat16* W1T = (__hip_bfloat16*)(ws);                         // 2048x512  bf16 (2 MB)
  __hip_bfloat16* W2T = (__hip_bfloat16*)(ws + 2097152);               // 512x2048  bf16 (2 MB)
  __hip_bfloat16* LNO = (__hip_bfloat16*)(ws + 4194304);               // 6144x512  bf16 (6 MB)
  __hip_bfloat16* H   = (__hip_bfloat16*)(ws + 4194304 + 6291456);     // 6144x2048 bf16 (24 MB)

  // K0: W1 (512x2048) -> W1T (2048x512); W2 (2048x512) -> W2T (512x2048)
  transpose_f32_bf16<<<dim3(2048 / 32, 512 / 32), dim3(32, 8), 0, stream>>>(W1, W1T, 512, 2048);
  transpose_f32_bf16<<<dim3(512 / 32, 2048 / 32), dim3(32, 8), 0, stream>>>(W2, W2T, 2048, 512);

  // K1: fused attention + LN -> LNO
  attn_ln_k<<<1024, 512, 0, stream>>>(x, pt, g, bta, LNO);

  // K2: h = gelu(LNO @ W1 + b1) -> H (bf16)
  gemm_bt<128, 128, true><<<dim3(2048 / 128, 6144 / 128), 256, 0, stream>>>(
      LNO, W1T, b1, (void*)H, 6144, 2048, 512);

  // K3: out = H @ W2 + b2 -> d_out (f32)
  gemm_bt<64, 64, false><<<dim3(512 / 64, 6144 / 64), 256, 0, stream>>>(
      H, W2T, b2, (void*)outp, 6144, 512, 2048);
}